// Round 8
// baseline (245.584 us; speedup 1.0000x reference)
//
#include <hip/hip_runtime.h>

typedef _Float16 half8 __attribute__((ext_vector_type(8)));
typedef _Float16 half4 __attribute__((ext_vector_type(4)));
typedef float floatx16 __attribute__((ext_vector_type(16)));

#define MFMA_F16(A, B, C) __builtin_amdgcn_mfma_f32_32x32x16_f16(A, B, C, 0, 0, 0)

constexpr int Bn = 4;     // batch
constexpr int Cc = 256;   // channels
constexpr int Cq = 32;    // C/8
constexpr int Nn = 4096;  // tokens (64*64)
constexpr float LOG2E = 1.44269504088896340736f;

__device__ inline floatx16 zero16() {
  floatx16 z;
#pragma unroll
  for (int i = 0; i < 16; ++i) z[i] = 0.f;
  return z;
}

// ---------------------------------------------------------------------------
// Kernel 0: W fp32 -> f16 (Wf scaled by log2e for exp2-domain softmax).
// ---------------------------------------------------------------------------
__global__ __launch_bounds__(256) void k_wconv(
    const float* __restrict__ Wf, const float* __restrict__ Wg,
    const float* __restrict__ Wh, _Float16* __restrict__ Wfh,
    _Float16* __restrict__ Wgh, _Float16* __restrict__ Whh) {
  int e = (blockIdx.x * 256 + threadIdx.x) * 4;
  const float* src;
  _Float16* dst;
  float sc = 1.f;
  if (e < 8192) { src = Wf + e; dst = Wfh + e; sc = LOG2E; }
  else if (e < 16384) { src = Wg + (e - 8192); dst = Wgh + (e - 8192); }
  else { src = Wh + (e - 16384); dst = Whh + (e - 16384); }
  float4 v = *(const float4*)src;
  half4 o;
  o[0] = (_Float16)(v.x * sc); o[1] = (_Float16)(v.y * sc);
  o[2] = (_Float16)(v.z * sc); o[3] = (_Float16)(v.w * sc);
  *(half4*)dst = o;
}

// ---------------------------------------------------------------------------
// Kernel 1: projections straight from x[b][c][n] — no transpose pass.
// B-fragment of x read in [c][n] layout: lane ml -> n (coalesced), k -> c
// (strided dword loads). Q^T/K^T token-major; V^T channel-major.
// ---------------------------------------------------------------------------
__global__ __launch_bounds__(256) void k_proj(
    const float* __restrict__ x,
    const _Float16* __restrict__ Wfh, const float* __restrict__ bf,
    const _Float16* __restrict__ Wgh, const float* __restrict__ bg,
    const _Float16* __restrict__ Whh, const float* __restrict__ bh,
    _Float16* __restrict__ Q, _Float16* __restrict__ K,
    _Float16* __restrict__ Vt) {
  int tid = threadIdx.x;
  int w = tid >> 6, lane = tid & 63;
  int ml = lane & 31, h = lane >> 5;
  int b = blockIdx.x >> 7, nt = blockIdx.x & 127;
  int n0 = nt * 32;
  const float* xb = x + (size_t)b * Cc * Nn + n0 + ml;

  for (int t = w; t < 10; t += 4) {
    const _Float16* W;
    const float* bias;
    float bscale = 1.f;
    int o0 = 0;
    if (t == 0) { W = Wfh; bias = bf; bscale = LOG2E; }
    else if (t == 1) { W = Wgh; bias = bg; }
    else { W = Whh + (size_t)(t - 2) * 32 * Cc; bias = bh + (t - 2) * 32; o0 = (t - 2) * 32; }

    floatx16 acc = zero16();
    const _Float16* wp = W + (size_t)ml * Cc + h * 8;
#pragma unroll
    for (int kc = 0; kc < 16; ++kc) {
      half8 a = *(const half8*)(wp + kc * 16);
      const float* xp = xb + (size_t)(kc * 16 + h * 8) * Nn;
      half8 bfr;
#pragma unroll
      for (int j = 0; j < 8; ++j) bfr[j] = (_Float16)xp[(size_t)j * Nn];
      acc = MFMA_F16(a, bfr, acc);
    }

    if (t < 2) {
      _Float16* dst = (t == 0) ? Q : K;
      _Float16* op = dst + ((size_t)b * Nn + n0 + ml) * Cq;
#pragma unroll
      for (int qd = 0; qd < 4; ++qd) {
        float4 bq = *(const float4*)(bias + 8 * qd + 4 * h);
        const float* bqp = (const float*)&bq;
#pragma unroll
        for (int i = 0; i < 4; ++i) {
          int crow = i + 8 * qd + 4 * h;
          op[crow] = (_Float16)(acc[4 * qd + i] + bqp[i] * bscale);
        }
      }
    } else {
      _Float16* op = Vt + ((size_t)b * Cc + o0) * (size_t)Nn + n0 + ml;
#pragma unroll
      for (int qd = 0; qd < 4; ++qd) {
        float4 bq = *(const float4*)(bias + 8 * qd + 4 * h);
        const float* bqp = (const float*)&bq;
#pragma unroll
        for (int i = 0; i < 4; ++i) {
          int crow = i + 8 * qd + 4 * h;
          op[(size_t)crow * Nn] = (_Float16)(acc[4 * qd + i] + bqp[i]);
        }
      }
    }
  }
}

// ---------------------------------------------------------------------------
// Kernel 2: pass-1 row max (log2-domain). MFMA bitwise identical to k_attn's
// S computation -> exp2(s - M) <= 1 exactly.
// ---------------------------------------------------------------------------
__global__ __launch_bounds__(512) void k_rowmax(const _Float16* __restrict__ Q,
                                                const _Float16* __restrict__ K,
                                                float* __restrict__ M) {
  __shared__ float red[8][32];
  int tid = threadIdx.x, w = tid >> 6, lane = tid & 63;
  int ml = lane & 31, h = lane >> 5;
  int b = blockIdx.x >> 7, mt = blockIdx.x & 127;
  int m0 = mt * 32;
  const _Float16* qp = Q + ((size_t)b * Nn + m0 + ml) * Cq + h * 8;
  half8 qb0 = *(const half8*)(qp);
  half8 qb1 = *(const half8*)(qp + 16);
  const _Float16* kp = K + ((size_t)b * Nn + w * 512 + ml) * Cq + h * 8;
  float mx = -3.0e38f;
  for (int t = 0; t < 16; ++t) {
    floatx16 s = zero16();
    half8 k0 = *(const half8*)(kp + (size_t)t * 32 * Cq);
    half8 k1 = *(const half8*)(kp + (size_t)t * 32 * Cq + 16);
    s = MFMA_F16(k0, qb0, s);
    s = MFMA_F16(k1, qb1, s);
#pragma unroll
    for (int i = 0; i < 16; ++i) mx = fmaxf(mx, s[i]);
  }
  mx = fmaxf(mx, __shfl_xor(mx, 32, 64));
  if (h == 0) red[w][ml] = mx;
  __syncthreads();
  if (tid < 32) {
    float m2 = red[0][tid];
#pragma unroll
    for (int i = 1; i < 8; ++i) m2 = fmaxf(m2, red[i][tid]);
    M[(size_t)b * Nn + m0 + tid] = m2;
  }
}

// ---------------------------------------------------------------------------
// Kernel 3: pass-2 attention v7 — m-split 32, NC=2, 1:2 LDS-read:MFMA.
// Grid: NC(2) x b(4) x mt(128) = 1024 blocks of 256 thr (4 waves).
// LDS 17 KB -> 4 blocks/CU = 16 waves/CU in 4 independent barrier groups;
// every (m,n) S element is computed and exp'd exactly ONCE (no duplication).
// S phase: wave w -> 32m x 32n subtile (n-stripe w) of the 32m x 128n P tile,
// exp2 -> LDS (XOR 16B-chunk swizzle, write b64, read b128 ~conflict-free).
// PV phase: wave w covers c in [w*64,(w+1)*64): per kc, 2 V half8 + 1 P b128
// + 2 MFMA (LDS reads per MFMA halved vs v3/v6).
// Single barrier/iter, double-buffered P. Unnormalized f16 O-partials +
// fp32 l-partials; k_fin combines.
// ---------------------------------------------------------------------------
__global__ __launch_bounds__(256, 4) void k_attn(
    const _Float16* __restrict__ Q, const _Float16* __restrict__ K,
    const _Float16* __restrict__ Vt, const float* __restrict__ M,
    _Float16* __restrict__ Opart, float* __restrict__ lpart, int nspan) {
  __shared__ _Float16 P[2 * 32 * 128];  // 16 KB double-buffered P tile
  __shared__ float lred[4][32];
  int tid = threadIdx.x, w = tid >> 6, lane = tid & 63;
  int ml = lane & 31, h = lane >> 5;
  int bx = blockIdx.x;
  int mt = bx & 127, b = (bx >> 7) & 3, nc = bx >> 9;
  int m0 = mt * 32;
  int nbase0 = nc * nspan;
  int sw = ml & 15;

  const _Float16* qpb = Q + ((size_t)b * Nn + m0 + ml) * Cq + h * 8;
  half8 qb0 = *(const half8*)(qpb);
  half8 qb1 = *(const half8*)(qpb + 16);
  float Mv = M[(size_t)b * Nn + m0 + ml];
  float lacc = 0.f;

  const _Float16* kbase =
      K + ((size_t)b * Nn + nbase0 + w * 32 + ml) * Cq + h * 8;
  int c0 = w * 64;
  const _Float16* vb0 =
      Vt + ((size_t)b * Cc + c0 + ml) * (size_t)Nn + nbase0 + h * 8;
  const _Float16* vb1 = vb0 + (size_t)32 * Nn;

  floatx16 o0 = zero16(), o1 = zero16();
  int iters = nspan >> 7;
  _Float16* pr = &P[ml * 128];  // row = m (col of S C-layout)

  for (int it = 0; it < iters; ++it) {
    int bufo = (it & 1) * (32 * 128);
    // ---- S phase: one 32m x 32n subtile per wave (n-stripe w) ----
    const _Float16* kp = kbase + (size_t)it * 128 * Cq;
    half8 k0 = *(const half8*)(kp);
    half8 k1 = *(const half8*)(kp + 16);
    floatx16 s = zero16();
    s = MFMA_F16(k0, qb0, s);
    s = MFMA_F16(k1, qb1, s);
#pragma unroll
    for (int q = 0; q < 4; ++q) {
      float p0 = exp2f(s[4 * q + 0] - Mv);
      float p1 = exp2f(s[4 * q + 1] - Mv);
      float p2 = exp2f(s[4 * q + 2] - Mv);
      float p3 = exp2f(s[4 * q + 3] - Mv);
      lacc += (p0 + p1) + (p2 + p3);
      half4 pk;
      pk[0] = (_Float16)p0; pk[1] = (_Float16)p1;
      pk[2] = (_Float16)p2; pk[3] = (_Float16)p3;
      // n = w*32 + 8q + 4h (+i) -> chunk = w*4+q, intra = 4h; XOR swizzle
      *(half4*)(pr + bufo + (((w * 4 + q) ^ sw)) * 8 + 4 * h) = pk;
    }
    __syncthreads();
    // ---- PV phase: wave = 64 c x 32 m: 2 V loads + 1 P read + 2 MFMA ----
    const _Float16* vp0 = vb0 + it * 128;
    const _Float16* vp1 = vb1 + it * 128;
#pragma unroll
    for (int kc = 0; kc < 8; ++kc) {
      half8 vf0 = *(const half8*)(vp0 + kc * 16);
      half8 vf1 = *(const half8*)(vp1 + kc * 16);
      int chunk = (kc * 2 + h) ^ sw;
      half8 pb = *(const half8*)(pr + bufo + chunk * 8);  // ds_read_b128
      o0 = MFMA_F16(vf0, pb, o0);
      o1 = MFMA_F16(vf1, pb, o1);
    }
  }

  // ---- l reduction: wave w holds partial l for its n-stripe ----
  lacc += __shfl_xor(lacc, 32, 64);
  if (h == 0) lred[w][ml] = lacc;
  __syncthreads();
  if (tid < 32) {
    float ls = lred[0][tid] + lred[1][tid] + lred[2][tid] + lred[3][tid];
    lpart[((size_t)nc * Bn + b) * Nn + m0 + tid] = ls;
  }

  // ---- store unnormalized O^T partials (f16) ----
  _Float16* opb =
      Opart + ((size_t)nc * Bn + b) * Cc * (size_t)Nn + m0 + ml;
#pragma unroll
  for (int r = 0; r < 16; ++r) {
    int crow = (r & 3) + 8 * (r >> 2) + 4 * h;
    opb[(size_t)(c0 + crow) * Nn] = (_Float16)o0[r];
    opb[(size_t)(c0 + 32 + crow) * Nn] = (_Float16)o1[r];
  }
}

// ---------------------------------------------------------------------------
// Kernel 4: combine chunk partials: out = gamma*(sum O)/(sum l) + input
// ---------------------------------------------------------------------------
__global__ __launch_bounds__(256) void k_fin(const _Float16* __restrict__ Op,
                                             const float* __restrict__ lp,
                                             const float* __restrict__ inp,
                                             const float* __restrict__ gamma,
                                             float* __restrict__ out, int NC) {
  int i4 = (blockIdx.x * 256 + threadIdx.x) * 4;
  int m = i4 & (Nn - 1);
  int bc = i4 >> 12;        // b*256 + c
  int b = bc >> 8;
  float ax = 0.f, ay = 0.f, az = 0.f, aw = 0.f;
  float lx = 0.f, ly = 0.f, lz = 0.f, lw = 0.f;
  for (int nc = 0; nc < NC; ++nc) {
    half4 o = *(const half4*)(Op + ((size_t)nc * Bn * Cc + bc) * Nn + m);
    float4 lv = *(const float4*)(lp + ((size_t)nc * Bn + b) * Nn + m);
    ax += (float)o[0]; ay += (float)o[1]; az += (float)o[2]; aw += (float)o[3];
    lx += lv.x; ly += lv.y; lz += lv.z; lw += lv.w;
  }
  float g = gamma[0];
  float4 xi = *(const float4*)(inp + (size_t)i4);
  float4 r;
  r.x = g * ax / lx + xi.x;
  r.y = g * ay / ly + xi.y;
  r.z = g * az / lz + xi.z;
  r.w = g * aw / lw + xi.w;
  *(float4*)(out + (size_t)i4) = r;
}

// ---------------------------------------------------------------------------
extern "C" void kernel_launch(void* const* d_in, const int* in_sizes, int n_in,
                              void* d_out, int out_size, void* d_ws,
                              size_t ws_size, hipStream_t stream) {
  const float* x = (const float*)d_in[0];
  const float* Wf = (const float*)d_in[1];
  const float* bf = (const float*)d_in[2];
  const float* Wg = (const float*)d_in[3];
  const float* bg = (const float*)d_in[4];
  const float* Wh = (const float*)d_in[5];
  const float* bh = (const float*)d_in[6];
  const float* gamma = (const float*)d_in[7];
  float* out = (float*)d_out;

  char* ws = (char*)d_ws;
  // Layout (bytes):
  //   Q      [0,        1048576)
  //   K      [1048576,  2097152)
  //   Vt     [2097152, 10485760)
  //   M      [10485760, 10551296)
  //   Wfh    [10551296, 10567680)
  //   Wgh    [10567680, 10584064)
  //   Whh    [10584064, 10715136)
  //   lpart  [10715136, 10846208)   (2 chunks x 64 KB)
  //   Opart  [10846208, 10846208 + NC*8388608)
  _Float16* Q  = (_Float16*)(ws);
  _Float16* K  = (_Float16*)(ws + 1048576);
  _Float16* Vt = (_Float16*)(ws + 2097152);
  float*    M  = (float*)   (ws + 10485760);
  _Float16* Wfh = (_Float16*)(ws + 10551296);
  _Float16* Wgh = (_Float16*)(ws + 10567680);
  _Float16* Whh = (_Float16*)(ws + 10584064);
  float*    lpart = (float*)(ws + 10715136);
  _Float16* Opart = (_Float16*)(ws + 10846208);

  size_t base = 10846208u;
  int NC = (ws_size >= base + 2u * 8388608u) ? 2 : 1;
  int nspan = Nn / NC;

  k_wconv<<<dim3(80), dim3(256), 0, stream>>>(Wf, Wg, Wh, Wfh, Wgh, Whh);
  k_proj<<<dim3(512), dim3(256), 0, stream>>>(x, Wfh, bf, Wgh, bg, Whh, bh, Q, K, Vt);
  k_rowmax<<<dim3(512), dim3(512), 0, stream>>>(Q, K, M);
  k_attn<<<dim3(NC * 512), dim3(256), 0, stream>>>(Q, K, Vt, M, Opart, lpart, nspan);
  k_fin<<<dim3(4096), dim3(256), 0, stream>>>(Opart, lpart, x, gamma, out, NC);
}

// Round 9
// 170.507 us; speedup vs baseline: 1.4403x; 1.4403x over previous
//
#include <hip/hip_runtime.h>

typedef _Float16 half8 __attribute__((ext_vector_type(8)));
typedef _Float16 half4 __attribute__((ext_vector_type(4)));
typedef float floatx16 __attribute__((ext_vector_type(16)));

#define MFMA_F16(A, B, C) __builtin_amdgcn_mfma_f32_32x32x16_f16(A, B, C, 0, 0, 0)

constexpr int Bn = 4;     // batch
constexpr int Cc = 256;   // channels
constexpr int Cq = 32;    // C/8
constexpr int Nn = 4096;  // tokens (64*64)
constexpr float LOG2E = 1.44269504088896340736f;

// Layouts (the round-9 change — kill VMEM scatter):
//   K4[b][cidx=0..3][n][8] : K fragment chunk cidx=(Cq>>3), dense across lanes
//   V8[b][nb=n>>3][c][8]   : V A-fragment, lane ml -> consecutive 16B chunks

__device__ inline floatx16 zero16() {
  floatx16 z;
#pragma unroll
  for (int i = 0; i < 16; ++i) z[i] = 0.f;
  return z;
}

// ---------------------------------------------------------------------------
// Kernel 0: W fp32 -> f16 (Wf scaled by log2e for exp2-domain softmax).
// ---------------------------------------------------------------------------
__global__ __launch_bounds__(256) void k_wconv(
    const float* __restrict__ Wf, const float* __restrict__ Wg,
    const float* __restrict__ Wh, _Float16* __restrict__ Wfh,
    _Float16* __restrict__ Wgh, _Float16* __restrict__ Whh) {
  int e = (blockIdx.x * 256 + threadIdx.x) * 4;
  const float* src;
  _Float16* dst;
  float sc = 1.f;
  if (e < 8192) { src = Wf + e; dst = Wfh + e; sc = LOG2E; }
  else if (e < 16384) { src = Wg + (e - 8192); dst = Wgh + (e - 8192); }
  else { src = Wh + (e - 16384); dst = Whh + (e - 16384); }
  float4 v = *(const float4*)src;
  half4 o;
  o[0] = (_Float16)(v.x * sc); o[1] = (_Float16)(v.y * sc);
  o[2] = (_Float16)(v.z * sc); o[3] = (_Float16)(v.w * sc);
  *(half4*)dst = o;
}

// ---------------------------------------------------------------------------
// Kernel 1: projections straight from x[b][c][n].
// Q token-major; K -> K4 tiled; V -> V8 tiled (coalesced k_attn fragments).
// ---------------------------------------------------------------------------
__global__ __launch_bounds__(256) void k_proj(
    const float* __restrict__ x,
    const _Float16* __restrict__ Wfh, const float* __restrict__ bf,
    const _Float16* __restrict__ Wgh, const float* __restrict__ bg,
    const _Float16* __restrict__ Whh, const float* __restrict__ bh,
    _Float16* __restrict__ Q, _Float16* __restrict__ K4,
    _Float16* __restrict__ V8) {
  int tid = threadIdx.x;
  int w = tid >> 6, lane = tid & 63;
  int ml = lane & 31, h = lane >> 5;
  int b = blockIdx.x >> 7, nt = blockIdx.x & 127;
  int n0 = nt * 32;
  const float* xb = x + (size_t)b * Cc * Nn + n0 + ml;

  for (int t = w; t < 10; t += 4) {
    const _Float16* W;
    const float* bias;
    float bscale = 1.f;
    int o0 = 0;
    if (t == 0) { W = Wfh; bias = bf; bscale = LOG2E; }
    else if (t == 1) { W = Wgh; bias = bg; }
    else { W = Whh + (size_t)(t - 2) * 32 * Cc; bias = bh + (t - 2) * 32; o0 = (t - 2) * 32; }

    floatx16 acc = zero16();
    const _Float16* wp = W + (size_t)ml * Cc + h * 8;
#pragma unroll
    for (int kc = 0; kc < 16; ++kc) {
      half8 a = *(const half8*)(wp + kc * 16);
      const float* xp = xb + (size_t)(kc * 16 + h * 8) * Nn;
      half8 bfr;
#pragma unroll
      for (int j = 0; j < 8; ++j) bfr[j] = (_Float16)xp[(size_t)j * Nn];
      acc = MFMA_F16(a, bfr, acc);
    }

    if (t == 0) {
      // Q token-major Q[b][n][o]
      _Float16* op = Q + ((size_t)b * Nn + n0 + ml) * Cq;
#pragma unroll
      for (int qd = 0; qd < 4; ++qd) {
        float4 bq = *(const float4*)(bias + 8 * qd + 4 * h);
        const float* bqp = (const float*)&bq;
#pragma unroll
        for (int i = 0; i < 4; ++i) {
          int crow = i + 8 * qd + 4 * h;
          op[crow] = (_Float16)(acc[4 * qd + i] + bqp[i] * bscale);
        }
      }
    } else if (t == 1) {
      // K4[b][crow>>3][n][crow&7]
#pragma unroll
      for (int qd = 0; qd < 4; ++qd) {
        float4 bq = *(const float4*)(bias + 8 * qd + 4 * h);
        const float* bqp = (const float*)&bq;
#pragma unroll
        for (int i = 0; i < 4; ++i) {
          int crow = i + 8 * qd + 4 * h;
          K4[(((size_t)b * 4 + (crow >> 3)) * Nn + n0 + ml) * 8 + (crow & 7)] =
              (_Float16)(acc[4 * qd + i] + bqp[i]);
        }
      }
    } else {
      // V8[b][(n0+ml)>>3][c][ml&7]
      size_t nb = (size_t)((n0 + ml) >> 3);
      _Float16* op = V8 + (((size_t)b * 512 + nb) * 256) * 8 + (ml & 7);
#pragma unroll
      for (int qd = 0; qd < 4; ++qd) {
        float4 bq = *(const float4*)(bias + 8 * qd + 4 * h);
        const float* bqp = (const float*)&bq;
#pragma unroll
        for (int i = 0; i < 4; ++i) {
          int crow = i + 8 * qd + 4 * h;
          op[(size_t)(o0 + crow) * 8] = (_Float16)(acc[4 * qd + i] + bqp[i]);
        }
      }
    }
  }
}

// ---------------------------------------------------------------------------
// Kernel 2: pass-1 row max (log2-domain), K4 coalesced loads.
// MFMA bitwise identical to k_attn's S -> exp2(s-M) <= 1 exactly.
// ---------------------------------------------------------------------------
__global__ __launch_bounds__(512) void k_rowmax(const _Float16* __restrict__ Q,
                                                const _Float16* __restrict__ K4,
                                                float* __restrict__ M) {
  __shared__ float red[8][32];
  int tid = threadIdx.x, w = tid >> 6, lane = tid & 63;
  int ml = lane & 31, h = lane >> 5;
  int b = blockIdx.x >> 7, mt = blockIdx.x & 127;
  int m0 = mt * 32;
  const _Float16* qp = Q + ((size_t)b * Nn + m0 + ml) * Cq + h * 8;
  half8 qb0 = *(const half8*)(qp);
  half8 qb1 = *(const half8*)(qp + 16);
  const _Float16* kp0 = K4 + (((size_t)b * 4 + h) * Nn + w * 512 + ml) * 8;
  const _Float16* kp1 = K4 + (((size_t)b * 4 + 2 + h) * Nn + w * 512 + ml) * 8;
  float mx = -3.0e38f;
  for (int t = 0; t < 16; ++t) {
    floatx16 s = zero16();
    half8 k0 = *(const half8*)(kp0 + (size_t)t * 32 * 8);
    half8 k1 = *(const half8*)(kp1 + (size_t)t * 32 * 8);
    s = MFMA_F16(k0, qb0, s);
    s = MFMA_F16(k1, qb1, s);
#pragma unroll
    for (int i = 0; i < 16; ++i) mx = fmaxf(mx, s[i]);
  }
  mx = fmaxf(mx, __shfl_xor(mx, 32, 64));
  if (h == 0) red[w][ml] = mx;
  __syncthreads();
  if (tid < 32) {
    float m2 = red[0][tid];
#pragma unroll
    for (int i = 1; i < 8; ++i) m2 = fmaxf(m2, red[i][tid]);
    M[(size_t)b * Nn + m0 + tid] = m2;
  }
}

// ---------------------------------------------------------------------------
// Kernel 3: pass-2 attention v8 = proven v3 structure + coalesced K4/V8.
// Grid: NC(2) x 4 x 64 blocks of 512 thr (8 waves), 2 blocks/CU.
// S phase: wave (msub,nq) -> 32m x 32n subtile of 64m x 128n P tile,
// exp2 -> LDS (XOR 16B-chunk swizzle; write b64, read b128 conflict-free).
// PV: wave w -> c0=w*32, both m-halves: per kc 1 coalesced V b128 +
// 2 P b128 + 2 MFMA. Single barrier/iter, double-buffered P.
// Unnormalized f16 O-partials + fp32 l-partials; k_fin combines.
// ---------------------------------------------------------------------------
__global__ __launch_bounds__(512, 4) void k_attn(
    const _Float16* __restrict__ Q, const _Float16* __restrict__ K4,
    const _Float16* __restrict__ V8, const float* __restrict__ M,
    _Float16* __restrict__ Opart, float* __restrict__ lpart, int nspan) {
  __shared__ _Float16 P[2 * 64 * 128];
  __shared__ float lred[8][32];
  int tid = threadIdx.x, w = tid >> 6, lane = tid & 63;
  int ml = lane & 31, h = lane >> 5;
  int msub = w & 1, nq = w >> 1;
  int bx = blockIdx.x;
  int mt = bx & 63, b = (bx >> 6) & 3, nc = bx >> 8;
  int m0 = mt * 64;
  int nbase0 = nc * nspan;
  int sw = ml & 15;

  const _Float16* qp = Q + ((size_t)b * Nn + m0 + msub * 32 + ml) * Cq + h * 8;
  half8 qb0 = *(const half8*)(qp);
  half8 qb1 = *(const half8*)(qp + 16);
  float Mv = M[(size_t)b * Nn + m0 + msub * 32 + ml];
  float lacc = 0.f;

  // K4 fragments: n = nbase0 + it*128 + nq*32 + ml  (coalesced across ml)
  const _Float16* k4b0 =
      K4 + (((size_t)b * 4 + h) * Nn + nbase0 + nq * 32 + ml) * 8;
  const _Float16* k4b1 =
      K4 + (((size_t)b * 4 + 2 + h) * Nn + nbase0 + nq * 32 + ml) * 8;

  int c0 = w * 32;
  // V8: nb = (nbase0>>3) + it*16 + kc*2 + h; elem ((b*512+nb)*256 + c)*8
  const _Float16* v8b =
      V8 + (((size_t)b * 512 + (nbase0 >> 3)) * 256 + c0 + ml) * 8;

  floatx16 o0 = zero16(), o1 = zero16();
  int iters = nspan >> 7;
  _Float16* pwbase = &P[(msub * 32 + ml) * 128];
  const _Float16* pr0 = &P[ml * 128];
  const _Float16* pr1 = &P[(32 + ml) * 128];

  for (int it = 0; it < iters; ++it) {
    int bufo = (it & 1) * (64 * 128);
    // ---- S phase ----
    {
      floatx16 s = zero16();
      half8 k0 = *(const half8*)(k4b0 + (size_t)it * 128 * 8);
      half8 k1 = *(const half8*)(k4b1 + (size_t)it * 128 * 8);
      s = MFMA_F16(k0, qb0, s);
      s = MFMA_F16(k1, qb1, s);
      _Float16* pw = pwbase + bufo;
#pragma unroll
      for (int q = 0; q < 4; ++q) {
        float p0 = exp2f(s[4 * q + 0] - Mv);
        float p1 = exp2f(s[4 * q + 1] - Mv);
        float p2 = exp2f(s[4 * q + 2] - Mv);
        float p3 = exp2f(s[4 * q + 3] - Mv);
        lacc += (p0 + p1) + (p2 + p3);
        half4 pk;
        pk[0] = (_Float16)p0; pk[1] = (_Float16)p1;
        pk[2] = (_Float16)p2; pk[3] = (_Float16)p3;
        *(half4*)(pw + ((nq * 4 + q) ^ sw) * 8 + 4 * h) = pk;  // ds_write_b64
      }
    }
    __syncthreads();
    // ---- PV phase: coalesced V + swizzled P reads ----
    {
      const _Float16* vp = v8b + (size_t)it * 16 * 2048;  // 2048 = 256*8
      const _Float16* p0b = pr0 + bufo;
      const _Float16* p1b = pr1 + bufo;
#pragma unroll
      for (int kc = 0; kc < 8; ++kc) {
        half8 vf = *(const half8*)(vp + (size_t)(kc * 2 + h) * 2048);
        int chunk = (kc * 2 + h) ^ sw;
        half8 pb0 = *(const half8*)(p0b + chunk * 8);  // ds_read_b128
        half8 pb1 = *(const half8*)(p1b + chunk * 8);
        o0 = MFMA_F16(vf, pb0, o0);
        o1 = MFMA_F16(vf, pb1, o1);
      }
    }
  }

  // ---- l reduction: wave w holds partial l for msub=w&1, n-stripe nq ----
  lacc += __shfl_xor(lacc, 32, 64);
  if (h == 0) lred[w][ml] = lacc;
  __syncthreads();
  if (w < 2 && h == 0) {
    float lsum = lred[w][ml] + lred[w + 2][ml] + lred[w + 4][ml] + lred[w + 6][ml];
    lpart[((size_t)nc * Bn + b) * Nn + m0 + w * 32 + ml] = lsum;
  }

  // ---- store unnormalized O^T partials (f16) ----
  _Float16* op0 = Opart + ((size_t)((size_t)nc * Bn + b) * Cc) * Nn + (m0 + ml);
#pragma unroll
  for (int r = 0; r < 16; ++r) {
    int c = c0 + (r & 3) + 8 * (r >> 2) + 4 * h;
    op0[(size_t)c * Nn] = (_Float16)o0[r];
    op0[(size_t)c * Nn + 32] = (_Float16)o1[r];
  }
}

// ---------------------------------------------------------------------------
// Kernel 4: combine chunk partials: out = gamma*(sum O)/(sum l) + input
// ---------------------------------------------------------------------------
__global__ __launch_bounds__(256) void k_fin(const _Float16* __restrict__ Op,
                                             const float* __restrict__ lp,
                                             const float* __restrict__ inp,
                                             const float* __restrict__ gamma,
                                             float* __restrict__ out, int NC) {
  int i4 = (blockIdx.x * 256 + threadIdx.x) * 4;
  int m = i4 & (Nn - 1);
  int bc = i4 >> 12;        // b*256 + c
  int b = bc >> 8;
  float ax = 0.f, ay = 0.f, az = 0.f, aw = 0.f;
  float lx = 0.f, ly = 0.f, lz = 0.f, lw = 0.f;
  for (int nc = 0; nc < NC; ++nc) {
    half4 o = *(const half4*)(Op + ((size_t)nc * Bn * Cc + bc) * Nn + m);
    float4 lv = *(const float4*)(lp + ((size_t)nc * Bn + b) * Nn + m);
    ax += (float)o[0]; ay += (float)o[1]; az += (float)o[2]; aw += (float)o[3];
    lx += lv.x; ly += lv.y; lz += lv.z; lw += lv.w;
  }
  float g = gamma[0];
  float4 xi = *(const float4*)(inp + (size_t)i4);
  float4 r;
  r.x = g * ax / lx + xi.x;
  r.y = g * ay / ly + xi.y;
  r.z = g * az / lz + xi.z;
  r.w = g * aw / lw + xi.w;
  *(float4*)(out + (size_t)i4) = r;
}

// ---------------------------------------------------------------------------
extern "C" void kernel_launch(void* const* d_in, const int* in_sizes, int n_in,
                              void* d_out, int out_size, void* d_ws,
                              size_t ws_size, hipStream_t stream) {
  const float* x = (const float*)d_in[0];
  const float* Wf = (const float*)d_in[1];
  const float* bf = (const float*)d_in[2];
  const float* Wg = (const float*)d_in[3];
  const float* bg = (const float*)d_in[4];
  const float* Wh = (const float*)d_in[5];
  const float* bh = (const float*)d_in[6];
  const float* gamma = (const float*)d_in[7];
  float* out = (float*)d_out;

  char* ws = (char*)d_ws;
  // Layout (bytes):
  //   Q      [0,        1048576)
  //   K4     [1048576,  2097152)
  //   V8     [2097152, 10485760)
  //   M      [10485760, 10551296)
  //   Wfh    [10551296, 10567680)
  //   Wgh    [10567680, 10584064)
  //   Whh    [10584064, 10715136)
  //   lpart  [10715136, 10846208)   (2 chunks x 64 KB)
  //   Opart  [10846208, 10846208 + NC*8388608)
  _Float16* Q  = (_Float16*)(ws);
  _Float16* K4 = (_Float16*)(ws + 1048576);
  _Float16* V8 = (_Float16*)(ws + 2097152);
  float*    M  = (float*)   (ws + 10485760);
  _Float16* Wfh = (_Float16*)(ws + 10551296);
  _Float16* Wgh = (_Float16*)(ws + 10567680);
  _Float16* Whh = (_Float16*)(ws + 10584064);
  float*    lpart = (float*)(ws + 10715136);
  _Float16* Opart = (_Float16*)(ws + 10846208);

  size_t base = 10846208u;
  int NC = (ws_size >= base + 2u * 8388608u) ? 2 : 1;
  int nspan = Nn / NC;

  k_wconv<<<dim3(80), dim3(256), 0, stream>>>(Wf, Wg, Wh, Wfh, Wgh, Whh);
  k_proj<<<dim3(512), dim3(256), 0, stream>>>(x, Wfh, bf, Wgh, bg, Whh, bh, Q, K4, V8);
  k_rowmax<<<dim3(512), dim3(512), 0, stream>>>(Q, K4, M);
  k_attn<<<dim3(NC * 256), dim3(512), 0, stream>>>(Q, K4, V8, M, Opart, lpart, nspan);
  k_fin<<<dim3(4096), dim3(256), 0, stream>>>(Opart, lpart, x, gamma, out, NC);
}